// Round 7
// baseline (307.560 us; speedup 1.0000x reference)
//
#include <hip/hip_runtime.h>
#include <hip/hip_bf16.h>
#include <cstdint>

#define TSEQ 4096
#define CDIM 2048
#define HDIM 128

typedef short bf8v __attribute__((ext_vector_type(8)));  // 8 bf16 raw bits (4 VGPRs)
typedef float f4v  __attribute__((ext_vector_type(4)));

__device__ __forceinline__ unsigned short f2b(float f) {
  union { float f; unsigned u; } v; v.f = f;
  unsigned u = v.u;
  return (unsigned short)((u + 0x7fffu + ((u >> 16) & 1u)) >> 16);  // RNE
}

__device__ __forceinline__ f4v mfma16(bf8v a, bf8v b, f4v c) {
  return __builtin_amdgcn_mfma_f32_16x16x32_bf16(a, b, c, 0, 0, 0);
}

// ---------------- Kernel 1: pack Wq|Wk|Wv into B-frag-major WB ----------------
// WB[(t24*64 + kk)*64 + lane][8], t24 = y*8 + t16 (output-col 16-tile), kk = k/32.
// Element e = W_y[t16*16 + (lane&15)][kk*32 + (lane>>4)*8 + e]  (B-frag layout).
__global__ void wcat_pack(const float* __restrict__ Wq, const float* __restrict__ Wk,
                          const float* __restrict__ Wv, unsigned short* __restrict__ WB) {
  int g = blockIdx.x * 256 + threadIdx.x;   // 0 .. 98303
  int lane = g & 63, kk = (g >> 6) & 63, t24 = g >> 12;
  int y = t24 >> 3, t16 = t24 & 7;
  int row = t16 * 16 + (lane & 15);
  int k   = kk * 32 + (lane >> 4) * 8;
  const float* W = (y == 0) ? Wq : ((y == 1) ? Wk : Wv);
  const float* src = W + (size_t)row * CDIM + k;
  float4 f0 = *(const float4*)(src);
  float4 f1 = *(const float4*)(src + 4);
  ushort4 o0, o1;
  o0.x = f2b(f0.x); o0.y = f2b(f0.y); o0.z = f2b(f0.z); o0.w = f2b(f0.w);
  o1.x = f2b(f1.x); o1.y = f2b(f1.y); o1.z = f2b(f1.z); o1.w = f2b(f1.w);
  unsigned short* d = WB + (size_t)g * 8;
  *(ushort4*)(d)     = o0;
  *(ushort4*)(d + 4) = o1;
}

// ---------------- Kernel 2: proj GEMM v4 — frag-major A staging, reg-direct B ------
// 64x128 tile, BK=64 (32 iters), 512 thr / 8 waves (2x4 wave grid, 32x32/wave).
// A: fp32 -> bf16 frag-major LDS (thread tid owns frag slot tid: zero-conflict
// sequential ds_write/ds_read). B: frag-major WB read straight to registers (L2).
// Epilogue writes frag-major QB/KA/VB (VB gets a 9th "ones" h-tile for row-sums).
__global__ __launch_bounds__(512, 4) void proj_gemm(const float* __restrict__ A,
                                                    const unsigned short* __restrict__ WB,
                                                    unsigned short* __restrict__ QB,
                                                    unsigned short* __restrict__ KA,
                                                    unsigned short* __restrict__ VB) {
  __shared__ union {
    unsigned short As[2][512][8];   // [buf][frag slot][8]  16 KB
    unsigned short Ct[64][132];     // epilogue             16.9 KB
  } sm;
  const int m0 = blockIdx.x * 64;
  const int y  = blockIdx.y;          // 0=q, 1=k, 2=v
  const int tid = threadIdx.x;
  const int lane = tid & 63;
  const int w = tid >> 6;             // 8 waves
  const int wm = (w & 1) * 32, wn = (w >> 1) * 32;
  const int llo = lane & 15, lhi = lane >> 4;

  f4v acc[2][2];
#pragma unroll
  for (int i = 0; i < 2; ++i)
#pragma unroll
    for (int j = 0; j < 2; ++j) acc[i][j] = (f4v){0.f, 0.f, 0.f, 0.f};

  // A staging: thread = (t16l = tid>>7, kk2 = (tid>>6)&1, lane) -> frag slot tid
  const int t16l = tid >> 7, kk2 = (tid >> 6) & 1;
  const float* aptr = A + (size_t)(m0 + t16l * 16 + llo) * CDIM + kk2 * 32 + lhi * 8;
  // B frags: wave w needs n-tiles nt24 = y*8 + (w>>1)*2 + j, kk = it*2 + ks
  const unsigned short* wb0 = WB + (((size_t)(y * 8 + (w >> 1) * 2) * 64) * 64 + lane) * 8;
  const unsigned short* wb1 = wb0 + (size_t)64 * 64 * 8;   // j=1 tile

  float4 fa0 = *(const float4*)(aptr);
  float4 fa1 = *(const float4*)(aptr + 4);
  {
    ushort4 o0, o1;
    o0.x = f2b(fa0.x); o0.y = f2b(fa0.y); o0.z = f2b(fa0.z); o0.w = f2b(fa0.w);
    o1.x = f2b(fa1.x); o1.y = f2b(fa1.y); o1.z = f2b(fa1.z); o1.w = f2b(fa1.w);
    *(ushort4*)&sm.As[0][tid][0] = o0;
    *(ushort4*)&sm.As[0][tid][4] = o1;
  }
  bf8v bcur[4], bnxt[4];  // [ks*2 + j]
#pragma unroll
  for (int ks = 0; ks < 2; ++ks) {
    bcur[ks * 2 + 0] = *(const bf8v*)(wb0 + (size_t)ks * 512);
    bcur[ks * 2 + 1] = *(const bf8v*)(wb1 + (size_t)ks * 512);
  }

  for (int it = 0; it < 32; ++it) {
    const int cur = it & 1;
    __syncthreads();  // buf[cur] complete
    if (it < 31) {
      fa0 = *(const float4*)(aptr + (it + 1) * 64);
      fa1 = *(const float4*)(aptr + (it + 1) * 64 + 4);
#pragma unroll
      for (int ks = 0; ks < 2; ++ks) {
        bnxt[ks * 2 + 0] = *(const bf8v*)(wb0 + ((size_t)(it + 1) * 2 + ks) * 512);
        bnxt[ks * 2 + 1] = *(const bf8v*)(wb1 + ((size_t)(it + 1) * 2 + ks) * 512);
      }
    }
    // A frags: sequential ds_read_b128, zero conflicts
    bf8v af[2][2];
#pragma unroll
    for (int i = 0; i < 2; ++i)
#pragma unroll
      for (int ks = 0; ks < 2; ++ks)
        af[i][ks] = *(const bf8v*)&sm.As[cur][(((w & 1) * 2 + i) * 2 + ks) * 64 + lane][0];
#pragma unroll
    for (int ks = 0; ks < 2; ++ks)
#pragma unroll
      for (int i = 0; i < 2; ++i)
#pragma unroll
        for (int j = 0; j < 2; ++j)
          acc[i][j] = mfma16(af[i][ks], bcur[ks * 2 + j], acc[i][j]);
    if (it < 31) {
      ushort4 o0, o1;
      o0.x = f2b(fa0.x); o0.y = f2b(fa0.y); o0.z = f2b(fa0.z); o0.w = f2b(fa0.w);
      o1.x = f2b(fa1.x); o1.y = f2b(fa1.y); o1.z = f2b(fa1.z); o1.w = f2b(fa1.w);
      *(ushort4*)&sm.As[cur ^ 1][tid][0] = o0;
      *(ushort4*)&sm.As[cur ^ 1][tid][4] = o1;
#pragma unroll
      for (int q = 0; q < 4; ++q) bcur[q] = bnxt[q];
    }
  }
  __syncthreads();  // done with staging buffers; union flips to Ct
#pragma unroll
  for (int i = 0; i < 2; ++i)
#pragma unroll
    for (int j = 0; j < 2; ++j)
#pragma unroll
      for (int r = 0; r < 4; ++r)
        sm.Ct[wm + i * 16 + lhi * 4 + r][wn + j * 16 + llo] = f2b(acc[i][j][r]);
  __syncthreads();
  if (y < 2) {
    unsigned short* dst = (y == 0) ? QB : KA;
    const size_t base16 = (size_t)(m0 >> 4);
#pragma unroll
    for (int p = 0; p < 2; ++p) {
      int g = p * 512 + tid;                  // 4 t16 * 4 kk * 64 = 1024
      int t16g = g >> 8, kk = (g >> 6) & 3, ln = g & 63;
      int lo = ln & 15, hi = ln >> 4;
      bf8v v = *(const bf8v*)&sm.Ct[t16g * 16 + lo][kk * 32 + hi * 8];
      *(bf8v*)(dst + (((base16 + t16g) * 4 + kk) * 64 + ln) * 8) = v;
    }
  } else {
    const size_t base32 = (size_t)(m0 >> 5);
#pragma unroll
    for (int p = 0; p < 3; ++p) {
      int g = p * 512 + tid;                  // 2 jbl * 9 ht * 64 = 1152
      if (g < 1152) {
        int jbl = g / 576;
        int ht  = (g % 576) >> 6;
        int ln  = g & 63;
        int lo = ln & 15, hi = ln >> 4;
        bf8v v;
        if (ht == 8) {
#pragma unroll
          for (int e = 0; e < 8; ++e) v[e] = (lo == 0) ? (short)0x3F80 : (short)0;
        } else {
#pragma unroll
          for (int e = 0; e < 8; ++e) v[e] = (short)sm.Ct[jbl * 32 + hi * 8 + e][ht * 16 + lo];
        }
        *(bf8v*)(VB + (((base32 + jbl) * 9 + ht) * 512 + (size_t)ln * 8)) = v;
      }
    }
  }
}

// ---------------- Kernel 3: flash attention v6 — software-pipelined (unchanged) ----
__global__ __launch_bounds__(256, 4) void attn6(const unsigned short* __restrict__ QB,
                                                const unsigned short* __restrict__ KA,
                                                const unsigned short* __restrict__ VB,
                                                float* __restrict__ out) {
  __shared__ union SM {
    unsigned short Ps[4][2][16][68];
    struct { float Om[4][16][68]; float Lm[4][16]; } mg;
  } sm;
  const int x = blockIdx.x;
  const int b = x & 3;
  const int u = x >> 2;
  const int g = u >> 6, r0 = u & 63;
  const int s = (g & 1) ? (g * 64 + 63 - r0) : (g * 64 + r0);
  const int lastjt = s >> 2;
  const int tid = threadIdx.x;
  const int w = tid >> 6, lane = tid & 63;
  const int llo = lane & 15, lhi = lane >> 4;
  const float scale = 0.022097086912079608f;  // 2048^-0.5

  bf8v aK[4];
  {
    const unsigned short* kp = KA + (size_t)(b * 256 + s) * 2048;
#pragma unroll
    for (int kk = 0; kk < 4; ++kk) aK[kk] = *(const bf8v*)(kp + (kk * 64 + lane) * 8);
  }

  f4v Oacc[9];
#pragma unroll
  for (int nt = 0; nt < 9; ++nt) Oacc[nt] = (f4v){0.f, 0.f, 0.f, 0.f};

  auto computeS = [&](int jtS, int buf) {
    const unsigned short* qp = QB + (size_t)(b * 256 + jtS * 4) * 2048;
#pragma unroll
    for (int ct = 0; ct < 4; ++ct) {
      f4v acc = (f4v){0.f, 0.f, 0.f, 0.f};
#pragma unroll
      for (int kk = 0; kk < 4; ++kk) {
        bf8v bq = *(const bf8v*)(qp + ((ct * 4 + kk) * 64 + lane) * 8);
        acc = mfma16(aK[kk], bq, acc);
      }
#pragma unroll
      for (int r = 0; r < 4; ++r) {
        float sv = acc[r];
        if (jtS == lastjt) {
          int j = jtS * 64 + ct * 16 + llo;
          int i = s * 16 + lhi * 4 + r;
          if (j > i) sv = -3.0e38f;
        }
        sm.Ps[w][buf][lhi * 4 + r][ct * 16 + llo] = f2b(__expf(sv * scale));
      }
    }
  };

  if (w <= lastjt) computeS(w, 0);
  int buf = 0;
  for (int jt = w; jt <= lastjt; jt += 4) {
    bf8v aP0 = *(const bf8v*)&sm.Ps[w][buf][llo][lhi * 8];
    bf8v aP1 = *(const bf8v*)&sm.Ps[w][buf][llo][32 + lhi * 8];
    if (jt + 4 <= lastjt) computeS(jt + 4, buf ^ 1);
    const unsigned short* vp = VB + (size_t)(b * 128 + jt * 2) * 4608;
#pragma unroll
    for (int nt = 0; nt < 9; ++nt) {
      f4v o = Oacc[nt];
      o = mfma16(aP0, *(const bf8v*)(vp + nt * 512 + (size_t)lane * 8), o);
      o = mfma16(aP1, *(const bf8v*)(vp + 4608 + nt * 512 + (size_t)lane * 8), o);
      Oacc[nt] = o;
    }
    buf ^= 1;
  }

#pragma unroll
  for (int half = 0; half < 2; ++half) {
    __syncthreads();
#pragma unroll
    for (int nt = 0; nt < 4; ++nt)
#pragma unroll
      for (int r = 0; r < 4; ++r)
        sm.mg.Om[w][lhi * 4 + r][nt * 16 + llo] = Oacc[half * 4 + nt][r];
    if (half == 0 && llo == 0) {
#pragma unroll
      for (int r = 0; r < 4; ++r) sm.mg.Lm[w][lhi * 4 + r] = Oacc[8][r];
    }
    __syncthreads();
    {
      int row = tid >> 4, c0 = (tid & 15) * 4;
      float L = sm.mg.Lm[0][row] + sm.mg.Lm[1][row] + sm.mg.Lm[2][row] + sm.mg.Lm[3][row];
      float inv = 1.0f / L;
      float* op = out + (size_t)(b * TSEQ + s * 16 + row) * HDIM + half * 64 + c0;
#pragma unroll
      for (int e = 0; e < 4; ++e) {
        float o = sm.mg.Om[0][row][c0 + e] + sm.mg.Om[1][row][c0 + e] +
                  sm.mg.Om[2][row][c0 + e] + sm.mg.Om[3][row][c0 + e];
        op[e] = o * inv;
      }
    }
  }
}

extern "C" void kernel_launch(void* const* d_in, const int* in_sizes, int n_in,
                              void* d_out, int out_size, void* d_ws, size_t ws_size,
                              hipStream_t stream) {
  const float* idx = (const float*)d_in[0];
  const float* Wq  = (const float*)d_in[1];
  const float* Wk  = (const float*)d_in[2];
  const float* Wv  = (const float*)d_in[3];
  float* out = (float*)d_out;
  char* ws = (char*)d_ws;
  unsigned short* WB = (unsigned short*)ws;                        // 1.57 MB
  unsigned short* QB = (unsigned short*)(ws + ((size_t)2  << 20)); // 4.2 MB
  unsigned short* KA = (unsigned short*)(ws + ((size_t)7  << 20)); // 4.2 MB
  unsigned short* VB = (unsigned short*)(ws + ((size_t)12 << 20)); // 4.72 MB

  wcat_pack<<<384, 256, 0, stream>>>(Wq, Wk, Wv, WB);
  proj_gemm<<<dim3(256, 3), 512, 0, stream>>>(idx, WB, QB, KA, VB);
  attn6<<<1024, 256, 0, stream>>>(QB, KA, VB, out);
}